// Round 4
// baseline (23268.466 us; speedup 1.0000x reference)
//
#include <hip/hip_runtime.h>
#include <hip/hip_bf16.h>

// CharRNN (MI-GRU x2, T=256, B=128, H=1024) + NCE loss.
// Strategy: hoist all input-side GEMMs out of the recurrence; recurrence runs as
// 4 small bf16-MFMA kernels per step with fused gate epilogues; fp32 state.

#define T_SEQ 256
#define BATCH 128
#define HD    1024

typedef __attribute__((ext_vector_type(8))) short short8v;
typedef __attribute__((ext_vector_type(4))) float f32x4;

static __device__ __forceinline__ short f2b(float v) {
  __hip_bfloat16 h = __float2bfloat16(v);
  return __builtin_bit_cast(short, h);
}
static __device__ __forceinline__ float b2f(short s) {
  return __bfloat162float(__builtin_bit_cast(__hip_bfloat16, s));
}
static __device__ __forceinline__ float sigm(float x) { return 1.f / (1.f + __expf(-x)); }
static __device__ __forceinline__ float splus(float x) {
  return fmaxf(x, 0.f) + log1pf(__expf(-fabsf(x)));
}

struct Acc22 { f32x4 a[2][2]; };

// Wave computes a [32 x 32] tile: C[row0..row0+31, cb..cb+31] = A[128,K] @ W[K,N],
// where WT is W transposed, row-major [N][K] bf16. A row-major [*,K] bf16.
// MFMA 16x16x32 bf16: A frag lane l: row=l&15, k=8*(l>>4)+j (contig 8 -> one 16B load).
static __device__ __forceinline__ void gemm_wave(
    const short* __restrict__ A, int lda, const short* __restrict__ WT, int ldk,
    int row0, int cb, int K, Acc22& o) {
  const int lane = threadIdx.x & 63;
  const int l15 = lane & 15, g = lane >> 4;
  f32x4 z = {0.f, 0.f, 0.f, 0.f};
  o.a[0][0] = z; o.a[0][1] = z; o.a[1][0] = z; o.a[1][1] = z;
  const short* a0 = A + (size_t)(row0 + l15) * lda + g * 8;
  const short* a1 = a0 + 16 * (size_t)lda;
  const short* b0 = WT + (size_t)(cb + l15) * ldk + g * 8;
  const short* b1 = b0 + 16 * (size_t)ldk;
  for (int k = 0; k < K; k += 32) {
    short8v av0 = *(const short8v*)(a0 + k);
    short8v av1 = *(const short8v*)(a1 + k);
    short8v bv0 = *(const short8v*)(b0 + k);
    short8v bv1 = *(const short8v*)(b1 + k);
    o.a[0][0] = __builtin_amdgcn_mfma_f32_16x16x32_bf16(av0, bv0, o.a[0][0], 0, 0, 0);
    o.a[0][1] = __builtin_amdgcn_mfma_f32_16x16x32_bf16(av0, bv1, o.a[0][1], 0, 0, 0);
    o.a[1][0] = __builtin_amdgcn_mfma_f32_16x16x32_bf16(av1, bv0, o.a[1][0], 0, 0, 0);
    o.a[1][1] = __builtin_amdgcn_mfma_f32_16x16x32_bf16(av1, bv1, o.a[1][1], 0, 0, 0);
  }
}

struct Params {
  const int *tok, *tgt, *nce;
  const float *emb, *win, *binp;
  const float *ag, *b1g, *b2g, *bg, *ac, *b1c, *b2c, *bc;
  const float *smw, *smb;
  short *embB, *winT, *WhgT0, *WhgT1, *WhcT0, *WhcT1, *WXC0T, *WXC1T;
  short *sampWT;
  float *sampb;
  short *X, *OUTb;
  float *h0f, *h1f; short *h0b, *h1b;
  short *rh0b, *rh1b;
  float *u0, *u1, *gh1, *cx1;
  float *gxc0a, *gxc0b;
  float *slog;
  float *dout;
};

// ---------- setup kernels ----------

__global__ void k_zero(float* __restrict__ p, int n, float* __restrict__ dout) {
  int i = blockIdx.x * 256 + threadIdx.x;
  if (i < n) p[i] = 0.f;
  if (blockIdx.x == 0 && threadIdx.x == 0) *dout = 0.f;
}

__global__ void k_conv(const float* __restrict__ s, short* __restrict__ d, int n) {
  int i = (blockIdx.x * 256 + threadIdx.x) * 4;
  if (i + 4 <= n) {
    float4 v = *(const float4*)(s + i);
    d[i] = f2b(v.x); d[i + 1] = f2b(v.y); d[i + 2] = f2b(v.z); d[i + 3] = f2b(v.w);
  }
}

// W [K][N] fp32 -> WT [N][K] bf16.  grid (N/32, K/32), block (32,8).
__global__ void k_transpose(const float* __restrict__ W, short* __restrict__ WT,
                            int K, int N) {
  __shared__ short tile[32][33];
  int nt = blockIdx.x, kt = blockIdx.y;
  int tx = threadIdx.x, ty = threadIdx.y;
#pragma unroll
  for (int r = 0; r < 4; r++) {
    int k = kt * 32 + ty + r * 8;
    int n = nt * 32 + tx;
    tile[ty + r * 8][tx] = f2b(W[(size_t)k * N + n]);
  }
  __syncthreads();
#pragma unroll
  for (int r = 0; r < 4; r++) {
    int n = nt * 32 + ty + r * 8;
    int k = kt * 32 + tx;
    WT[(size_t)n * K + k] = tile[tx][ty + r * 8];
  }
}

__global__ void k_sampw(Params p) {
  int s = blockIdx.x;                       // 64 sample rows
  int row = p.nce[s];
  for (int j = threadIdx.x; j < HD; j += 256)
    p.sampWT[s * HD + j] = f2b(p.smw[(size_t)row * HD + j]);
  if (threadIdx.x == 0) p.sampb[s] = p.smb[row];
}

// X[t*128+b, :] = embedding[input_data[b,t]] @ win + bin.  grid 8192 (=256 mtiles * 32 ntiles)
__global__ __launch_bounds__(256) void k_xproj(Params p) {
  int blk = blockIdx.x;
  int mt = blk >> 5, nt = blk & 31;
  int w = threadIdx.x >> 6, lane = threadIdx.x & 63, l15 = lane & 15, g = lane >> 4;
  int row0 = mt * 128 + w * 32, cb = nt * 32;
  const short* ap[2];
#pragma unroll
  for (int mi = 0; mi < 2; mi++) {
    int r = row0 + mi * 16 + l15;
    int tt = r >> 7, bb = r & 127;
    int tk = p.tok[bb * T_SEQ + tt];
    ap[mi] = p.embB + (size_t)tk * 256 + g * 8;
  }
  f32x4 z = {0.f, 0.f, 0.f, 0.f};
  Acc22 acc; acc.a[0][0] = z; acc.a[0][1] = z; acc.a[1][0] = z; acc.a[1][1] = z;
  const short* b0 = p.winT + (size_t)(cb + l15) * 256 + g * 8;
  const short* b1 = b0 + 16 * 256;
  for (int k = 0; k < 256; k += 32) {
    short8v av0 = *(const short8v*)(ap[0] + k);
    short8v av1 = *(const short8v*)(ap[1] + k);
    short8v bv0 = *(const short8v*)(b0 + k);
    short8v bv1 = *(const short8v*)(b1 + k);
    acc.a[0][0] = __builtin_amdgcn_mfma_f32_16x16x32_bf16(av0, bv0, acc.a[0][0], 0, 0, 0);
    acc.a[0][1] = __builtin_amdgcn_mfma_f32_16x16x32_bf16(av0, bv1, acc.a[0][1], 0, 0, 0);
    acc.a[1][0] = __builtin_amdgcn_mfma_f32_16x16x32_bf16(av1, bv0, acc.a[1][0], 0, 0, 0);
    acc.a[1][1] = __builtin_amdgcn_mfma_f32_16x16x32_bf16(av1, bv1, acc.a[1][1], 0, 0, 0);
  }
#pragma unroll
  for (int mi = 0; mi < 2; mi++)
#pragma unroll
    for (int ni = 0; ni < 2; ni++)
#pragma unroll
      for (int i = 0; i < 4; i++) {
        int row = row0 + mi * 16 + g * 4 + i;
        int col = cb + ni * 16 + l15;
        p.X[(size_t)row * HD + col] = f2b(acc.a[mi][ni][i] + p.binp[col]);
      }
}

// gxc0 for t=0: X[0:128] @ [Wxg0|Wxc0]  -> gxc0a [128][3072].  grid 96.
__global__ __launch_bounds__(256) void k_gxc0init(Params p) {
  int blk = blockIdx.x;
  int w = threadIdx.x >> 6, lane = threadIdx.x & 63, l15 = lane & 15, g = lane >> 4;
  int row0 = w * 32, cb = blk * 32;
  Acc22 acc;
  gemm_wave(p.X, HD, p.WXC0T, HD, row0, cb, HD, acc);
#pragma unroll
  for (int mi = 0; mi < 2; mi++)
#pragma unroll
    for (int ni = 0; ni < 2; ni++)
#pragma unroll
      for (int i = 0; i < 4; i++) {
        int row = row0 + mi * 16 + g * 4 + i;
        int col = cb + ni * 16 + l15;
        p.gxc0a[row * 3072 + col] = acc.a[mi][ni][i];
      }
}

// ---------- recurrence: 4 kernels per step ----------

// K1: gh0 = h0@Whg0 (blocks 0-63, epilogue -> rh0,u0) ; gh1 = h1@Whg1 raw (blocks 64-127)
__global__ __launch_bounds__(256) void k_step1(Params p, int t) {
  int blk = blockIdx.x;
  int w = threadIdx.x >> 6, lane = threadIdx.x & 63, l15 = lane & 15, g = lane >> 4;
  int row0 = w * 32;
  bool L0 = blk < 64;
  int cb = (L0 ? blk : blk - 64) * 32;
  const float* gxc = (t & 1) ? p.gxc0b : p.gxc0a;
  Acc22 acc;
  gemm_wave(L0 ? p.h0b : p.h1b, HD, L0 ? p.WhgT0 : p.WhgT1, HD, row0, cb, HD, acc);
#pragma unroll
  for (int mi = 0; mi < 2; mi++)
#pragma unroll
    for (int ni = 0; ni < 2; ni++)
#pragma unroll
      for (int i = 0; i < 4; i++) {
        int row = row0 + mi * 16 + g * 4 + i;
        int col = cb + ni * 16 + l15;
        float gh = acc.a[mi][ni][i];
        if (L0) {
          float gx = gxc[row * 3072 + col];
          float gv = sigm(p.ag[col] * gx * gh + p.b1g[col] * gx + p.b2g[col] * gh + p.bg[col]);
          if (col < HD) p.rh0b[row * HD + col] = f2b(gv * p.h0f[row * HD + col]);
          else          p.u0[row * HD + col - HD] = gv;
        } else {
          p.gh1[row * 2048 + col] = gh;
        }
      }
}

// K2: ch0 = rh0@Whc0 ; epilogue -> h0 update. grid 32.
__global__ __launch_bounds__(256) void k_step2(Params p, int t) {
  int blk = blockIdx.x;
  int w = threadIdx.x >> 6, lane = threadIdx.x & 63, l15 = lane & 15, g = lane >> 4;
  int row0 = w * 32, cb = blk * 32;
  const float* gxc = (t & 1) ? p.gxc0b : p.gxc0a;
  Acc22 acc;
  gemm_wave(p.rh0b, HD, p.WhcT0, HD, row0, cb, HD, acc);
#pragma unroll
  for (int mi = 0; mi < 2; mi++)
#pragma unroll
    for (int ni = 0; ni < 2; ni++)
#pragma unroll
      for (int i = 0; i < 4; i++) {
        int row = row0 + mi * 16 + g * 4 + i;
        int col = cb + ni * 16 + l15;
        float ch = acc.a[mi][ni][i];
        float cx = gxc[row * 3072 + 2048 + col];
        float cv = tanhf(p.ac[col] * cx * ch + p.b1c[col] * cx + p.b2c[col] * ch + p.bc[col]);
        float un = p.u0[row * HD + col];
        float ho = p.h0f[row * HD + col];
        float hn = un * ho + (1.f - un) * cv;
        p.h0f[row * HD + col] = hn;
        p.h0b[row * HD + col] = f2b(hn);
      }
}

// K3: [gx1|cx1] = h0new @ [Wxg1|Wxc1]; gate epilogue for L1. grid 96.
__global__ __launch_bounds__(256) void k_step3(Params p, int t) {
  int blk = blockIdx.x;
  int w = threadIdx.x >> 6, lane = threadIdx.x & 63, l15 = lane & 15, g = lane >> 4;
  int row0 = w * 32, cb = blk * 32;
  Acc22 acc;
  gemm_wave(p.h0b, HD, p.WXC1T, HD, row0, cb, HD, acc);
#pragma unroll
  for (int mi = 0; mi < 2; mi++)
#pragma unroll
    for (int ni = 0; ni < 2; ni++)
#pragma unroll
      for (int i = 0; i < 4; i++) {
        int row = row0 + mi * 16 + g * 4 + i;
        int col = cb + ni * 16 + l15;
        float v = acc.a[mi][ni][i];
        if (col < 2048) {
          float gh = p.gh1[row * 2048 + col];
          float gv = sigm(p.ag[2048 + col] * v * gh + p.b1g[2048 + col] * v +
                          p.b2g[2048 + col] * gh + p.bg[2048 + col]);
          if (col < HD) p.rh1b[row * HD + col] = f2b(gv * p.h1f[row * HD + col]);
          else          p.u1[row * HD + col - HD] = gv;
        } else {
          p.cx1[row * HD + col - 2048] = v;
        }
      }
}

// K4: ch1 = rh1@Whc1 -> h1 update + OUT row (blocks 0-31);
//     gxc0 for step t+1 = X[t+1]@[Wxg0|Wxc0] (blocks 32-127, skip at t=255)
__global__ __launch_bounds__(256) void k_step4(Params p, int t) {
  int blk = blockIdx.x;
  int w = threadIdx.x >> 6, lane = threadIdx.x & 63, l15 = lane & 15, g = lane >> 4;
  int row0 = w * 32;
  if (blk < 32) {
    int cb = blk * 32;
    Acc22 acc;
    gemm_wave(p.rh1b, HD, p.WhcT1, HD, row0, cb, HD, acc);
#pragma unroll
    for (int mi = 0; mi < 2; mi++)
#pragma unroll
      for (int ni = 0; ni < 2; ni++)
#pragma unroll
        for (int i = 0; i < 4; i++) {
          int row = row0 + mi * 16 + g * 4 + i;
          int col = cb + ni * 16 + l15;
          float ch = acc.a[mi][ni][i];
          float cx = p.cx1[row * HD + col];
          float cv = tanhf(p.ac[HD + col] * cx * ch + p.b1c[HD + col] * cx +
                           p.b2c[HD + col] * ch + p.bc[HD + col]);
          float un = p.u1[row * HD + col];
          float ho = p.h1f[row * HD + col];
          float hn = un * ho + (1.f - un) * cv;
          p.h1f[row * HD + col] = hn;
          p.h1b[row * HD + col] = f2b(hn);
          p.OUTb[((size_t)t * BATCH + row) * HD + col] = f2b(hn);
        }
  } else {
    if (t == T_SEQ - 1) return;
    int cb = (blk - 32) * 32;
    const short* A = p.X + (size_t)(t + 1) * BATCH * HD;
    float* outb = ((t + 1) & 1) ? p.gxc0b : p.gxc0a;
    Acc22 acc;
    gemm_wave(A, HD, p.WXC0T, HD, row0, cb, HD, acc);
#pragma unroll
    for (int mi = 0; mi < 2; mi++)
#pragma unroll
      for (int ni = 0; ni < 2; ni++)
#pragma unroll
        for (int i = 0; i < 4; i++) {
          int row = row0 + mi * 16 + g * 4 + i;
          int col = cb + ni * 16 + l15;
          outb[row * 3072 + col] = acc.a[mi][ni][i];
        }
  }
}

// ---------- NCE ----------

// samp_logits = OUT @ sampW^T + sampb.  grid 512 (=256 mtiles * 2 ntiles)
__global__ __launch_bounds__(256) void k_nce_gemm(Params p) {
  int blk = blockIdx.x;
  int mt = blk >> 1, nt = blk & 1;
  int w = threadIdx.x >> 6, lane = threadIdx.x & 63, l15 = lane & 15, g = lane >> 4;
  int row0 = w * 32, cb = nt * 32;
  Acc22 acc;
  gemm_wave(p.OUTb + (size_t)mt * 128 * HD, HD, p.sampWT, HD, row0, cb, HD, acc);
#pragma unroll
  for (int mi = 0; mi < 2; mi++)
#pragma unroll
    for (int ni = 0; ni < 2; ni++)
#pragma unroll
      for (int i = 0; i < 4; i++) {
        int row = mt * 128 + row0 + mi * 16 + g * 4 + i;
        int col = cb + ni * 16 + l15;
        p.slog[(size_t)row * 64 + col] = acc.a[mi][ni][i] + p.sampb[col];
      }
}

// loss: wave per (b,t) row; true-logit dot (fp32 softmax_w) + softplus reduction.
// Each block adds its (already 1/32768-scaled) contribution to dout.
__global__ __launch_bounds__(256) void k_loss(Params p) {
  __shared__ float acc4[4];
  int w = threadIdx.x >> 6, lane = threadIdx.x & 63;
  int r = blockIdx.x * 4 + w;            // flatten order [b][t]
  int b = r >> 8, t = r & 255;
  int q = t * BATCH + b;                 // OUT row order [t][b]
  int label = p.tgt[r];
  const short* orow = p.OUTb + (size_t)q * HD;
  const float4* t4 = (const float4*)(p.smw + (size_t)label * HD) + lane * 4;
  float s = 0.f;
  const short8v* o8 = (const short8v*)(orow + lane * 16);
#pragma unroll
  for (int u2 = 0; u2 < 2; u2++) {
    short8v ov = o8[u2];
    float4 ta = t4[u2 * 2], tb = t4[u2 * 2 + 1];
    s += b2f(ov[0]) * ta.x + b2f(ov[1]) * ta.y + b2f(ov[2]) * ta.z + b2f(ov[3]) * ta.w;
    s += b2f(ov[4]) * tb.x + b2f(ov[5]) * tb.y + b2f(ov[6]) * tb.z + b2f(ov[7]) * tb.w;
  }
  for (int off = 32; off; off >>= 1) s += __shfl_down(s, off);
  float tl = __shfl(s, 0) + p.smb[label];
  float sl = p.slog[(size_t)q * 64 + lane];
  float v = splus(sl);
  for (int off = 32; off; off >>= 1) v += __shfl_down(v, off);
  if (lane == 0) acc4[w] = v + splus(-tl);
  __syncthreads();
  if (threadIdx.x == 0)
    atomicAdd(p.dout, (acc4[0] + acc4[1] + acc4[2] + acc4[3]) * (1.f / 32768.f));
}

// ---------- host ----------

extern "C" void kernel_launch(void* const* d_in, const int* in_sizes, int n_in,
                              void* d_out, int out_size, void* d_ws, size_t ws_size,
                              hipStream_t stream) {
  Params p;
  p.tok = (const int*)d_in[0];
  p.tgt = (const int*)d_in[1];
  p.nce = (const int*)d_in[2];
  p.emb = (const float*)d_in[3];
  p.win = (const float*)d_in[4];
  p.binp = (const float*)d_in[5];
  const float* Wxg = (const float*)d_in[6];
  const float* Whg = (const float*)d_in[7];
  p.ag = (const float*)d_in[8];
  p.b1g = (const float*)d_in[9];
  p.b2g = (const float*)d_in[10];
  p.bg = (const float*)d_in[11];
  const float* Wxc = (const float*)d_in[12];
  const float* Whc = (const float*)d_in[13];
  p.ac = (const float*)d_in[14];
  p.b1c = (const float*)d_in[15];
  p.b2c = (const float*)d_in[16];
  p.bc = (const float*)d_in[17];
  p.smw = (const float*)d_in[18];
  p.smb = (const float*)d_in[19];
  p.dout = (float*)d_out;

  char* w = (char*)d_ws;
  size_t off = 0;
  auto alloc = [&](size_t bytes) -> void* {
    void* q = w + off;
    off += (bytes + 255) & ~(size_t)255;
    return q;
  };
  p.embB   = (short*)alloc((size_t)16384 * 256 * 2);
  p.winT   = (short*)alloc((size_t)1024 * 256 * 2);
  p.WhgT0  = (short*)alloc((size_t)2048 * 1024 * 2);
  p.WhgT1  = (short*)alloc((size_t)2048 * 1024 * 2);
  p.WhcT0  = (short*)alloc((size_t)1024 * 1024 * 2);
  p.WhcT1  = (short*)alloc((size_t)1024 * 1024 * 2);
  p.WXC0T  = (short*)alloc((size_t)3072 * 1024 * 2);
  p.WXC1T  = (short*)alloc((size_t)3072 * 1024 * 2);
  p.sampWT = (short*)alloc((size_t)64 * 1024 * 2);
  p.sampb  = (float*)alloc(64 * 4);
  p.X      = (short*)alloc((size_t)32768 * 1024 * 2);
  p.OUTb   = (short*)alloc((size_t)32768 * 1024 * 2);
  p.h0f    = (float*)alloc((size_t)BATCH * HD * 4);   // h0f,h1f,h0b,h1b contiguous (zeroed together)
  p.h1f    = (float*)alloc((size_t)BATCH * HD * 4);
  p.h0b    = (short*)alloc((size_t)BATCH * HD * 2);
  p.h1b    = (short*)alloc((size_t)BATCH * HD * 2);
  p.rh0b   = (short*)alloc((size_t)BATCH * HD * 2);
  p.rh1b   = (short*)alloc((size_t)BATCH * HD * 2);
  p.u0     = (float*)alloc((size_t)BATCH * HD * 4);
  p.u1     = (float*)alloc((size_t)BATCH * HD * 4);
  p.gh1    = (float*)alloc((size_t)BATCH * 2048 * 4);
  p.cx1    = (float*)alloc((size_t)BATCH * HD * 4);
  p.gxc0a  = (float*)alloc((size_t)BATCH * 3072 * 4);
  p.gxc0b  = (float*)alloc((size_t)BATCH * 3072 * 4);
  p.slog   = (float*)alloc((size_t)32768 * 64 * 4);

  // zero h state (1.5MB contiguous) + d_out
  k_zero<<<1536, 256, 0, stream>>>(p.h0f, 393216, p.dout);
  // fp32 -> bf16 conversion (embedding only)
  k_conv<<<4096, 256, 0, stream>>>(p.emb, p.embB, 16384 * 256);
  // weight transposes (W [K][N] fp32 -> WT [N][K] bf16)
  dim3 tb(32, 8);
  k_transpose<<<dim3(32, 8),  tb, 0, stream>>>(p.win, p.winT, 256, 1024);
  k_transpose<<<dim3(64, 32), tb, 0, stream>>>(Whg, p.WhgT0, 1024, 2048);
  k_transpose<<<dim3(64, 32), tb, 0, stream>>>(Whg + (size_t)1024 * 2048, p.WhgT1, 1024, 2048);
  k_transpose<<<dim3(32, 32), tb, 0, stream>>>(Whc, p.WhcT0, 1024, 1024);
  k_transpose<<<dim3(32, 32), tb, 0, stream>>>(Whc + (size_t)1024 * 1024, p.WhcT1, 1024, 1024);
  k_transpose<<<dim3(64, 32), tb, 0, stream>>>(Wxg, p.WXC0T, 1024, 2048);
  k_transpose<<<dim3(32, 32), tb, 0, stream>>>(Wxc, p.WXC0T + (size_t)2048 * 1024, 1024, 1024);
  k_transpose<<<dim3(64, 32), tb, 0, stream>>>(Wxg + (size_t)1024 * 2048, p.WXC1T, 1024, 2048);
  k_transpose<<<dim3(32, 32), tb, 0, stream>>>(Wxc + (size_t)1024 * 1024, p.WXC1T + (size_t)2048 * 1024, 1024, 1024);
  // NCE sample weights
  k_sampw<<<64, 256, 0, stream>>>(p);
  // X = emb_gather @ win + bin  (layout [t][b][:])
  k_xproj<<<8192, 256, 0, stream>>>(p);
  // gxc0 for t=0
  k_gxc0init<<<96, 256, 0, stream>>>(p);

  // recurrence
  for (int t = 0; t < T_SEQ; t++) {
    k_step1<<<128, 256, 0, stream>>>(p, t);
    k_step2<<<32, 256, 0, stream>>>(p, t);
    k_step3<<<96, 256, 0, stream>>>(p, t);
    k_step4<<<128, 256, 0, stream>>>(p, t);
  }

  // NCE tail
  k_nce_gemm<<<512, 256, 0, stream>>>(p);
  k_loss<<<8192, 256, 0, stream>>>(p);
}